// Round 1
// baseline (380.383 us; speedup 1.0000x reference)
//
#include <hip/hip_runtime.h>
#include <stdint.h>

#define PRIME1 73856093u
#define PRIME2 19349663u
#define PRIME3 83492791u
#define PRIME4 2654435761u

// K1: compute bucket per point, write bucket output (as float), and per-chunk
// histogram into workspace chunk_hist[C][NB].
__global__ void k_bucket_hist(const float* __restrict__ coords,
                              const int* __restrict__ seps, int B,
                              const int* __restrict__ hash_op_p,
                              int N, int NB, int chunk,
                              float* __restrict__ out_bucket,
                              int* __restrict__ chunk_hist) {
    extern __shared__ int hist[];        // NB ints
    __shared__ int s_seps[128];
    const int tid = threadIdx.x;
    for (int i = tid; i < NB; i += blockDim.x) hist[i] = 0;
    const int Bc = B < 128 ? B : 128;
    if (tid < Bc) s_seps[tid] = seps[tid];
    __syncthreads();

    const uint32_t hop = (uint32_t)hash_op_p[0];
    const int start = blockIdx.x * chunk;
    const int end   = min(start + chunk, N);
    for (int i = start + tid; i < end; i += blockDim.x) {
        const float x = coords[3 * (size_t)i + 0];
        const float y = coords[3 * (size_t)i + 1];
        const float z = coords[3 * (size_t)i + 2];
        const uint32_t vx = (uint32_t)(int32_t)floorf(x);
        const uint32_t vy = (uint32_t)(int32_t)floorf(y);
        const uint32_t vz = (uint32_t)(int32_t)floorf(z);
        uint32_t bid = 0;
        for (int j = 0; j < Bc; j++) bid += (s_seps[j] <= i) ? 1u : 0u; // searchsorted 'right'
        uint32_t h = vx * PRIME1 ^ vy * PRIME2 ^ vz * PRIME3 ^ (bid * PRIME4);
        h += hop;
        const uint32_t b = h % (uint32_t)NB;
        out_bucket[i] = (float)b;
        atomicAdd(&hist[b], 1);
    }
    __syncthreads();
    int* dst = chunk_hist + (size_t)blockIdx.x * NB;
    for (int i = tid; i < NB; i += blockDim.x) dst[i] = hist[i];
}

// K2: per-bucket exclusive prefix across chunks (in place), total -> counts.
__global__ void k_prefix(int* __restrict__ chunk_hist, int C, int NB,
                         float* __restrict__ out_counts) {
    const int b = blockIdx.x * blockDim.x + threadIdx.x;
    if (b >= NB) return;
    int run = 0;
    for (int c = 0; c < C; c++) {
        const size_t idx = (size_t)c * NB + b;
        const int v = chunk_hist[idx];
        chunk_hist[idx] = run;
        run += v;
    }
    out_counts[b] = (float)run;
}

// K3: stable within-bucket rank (arrival order) + scatter of coords.
__global__ void k_scatter(const float* __restrict__ coords,
                          const float* __restrict__ bucket_f,
                          const int* __restrict__ chunk_base,
                          int N, int NB, int chunk,
                          float* __restrict__ out_sc) {
    extern __shared__ int hist[];        // NB running counters, seeded with chunk base
    const int tid = threadIdx.x;
    const int* src = chunk_base + (size_t)blockIdx.x * NB;
    for (int i = tid; i < NB; i += blockDim.x) hist[i] = src[i];
    __syncthreads();

    const int start = blockIdx.x * chunk;
    const int end   = min(start + chunk, N);
    int len = end - start; if (len < 0) len = 0;
    const int nbatch = (len + (int)blockDim.x - 1) / (int)blockDim.x;
    const int lane = tid & 63;
    const int wv   = tid >> 6;

    for (int t = 0; t < nbatch; t++) {
        const int i = start + t * (int)blockDim.x + tid;
        const bool valid = (i < end);
        const int b = valid ? (int)bucket_f[i] : -1;

        // Within-wave stable match: rank = earlier same-bucket lanes,
        // cnt = group size, leader = first same-bucket lane.
        int rank = 0, cnt = 0, leader = -1;
        #pragma unroll
        for (int j = 0; j < 64; j++) {
            const int bj = __shfl(b, j, 64);
            const bool m = (bj == b);
            cnt    += m ? 1 : 0;
            rank   += (m && j < lane) ? 1 : 0;
            leader  = (m && leader < 0) ? j : leader;
        }

        // Cross-wave serialization: waves take turns (arrival order) to claim
        // their group's base from the running LDS histogram.
        int basev = 0;
        for (int w = 0; w < 4; w++) {
            if (wv == w) {
                int old = 0;
                if (b >= 0 && rank == 0) old = atomicAdd(&hist[b], cnt);
                basev = __shfl(old, leader, 64);
            }
            __syncthreads();
        }

        if (valid) {
            const int r = basev + rank;
            if (r < 512) {
                const size_t slot = ((size_t)b * 512 + (size_t)r) * 3;
                out_sc[slot + 0] = coords[3 * (size_t)i + 0];
                out_sc[slot + 1] = coords[3 * (size_t)i + 1];
                out_sc[slot + 2] = coords[3 * (size_t)i + 2];
            }
        }
    }
}

extern "C" void kernel_launch(void* const* d_in, const int* in_sizes, int n_in,
                              void* d_out, int out_size, void* d_ws, size_t ws_size,
                              hipStream_t stream) {
    const float* coords  = (const float*)d_in[0];
    const int*   seps    = (const int*)d_in[1];
    const int*   hash_op = (const int*)d_in[2];

    const int N = in_sizes[0] / 3;
    const int B = in_sizes[1];
    const int pad_to = ((N + 511) / 512) * 512;
    const int NB = pad_to / 512;

    float* out        = (float*)d_out;
    float* out_counts = out + (size_t)pad_to * 3;
    float* out_bucket = out_counts + NB;

    int* chunk_hist = (int*)d_ws;
    int C = (int)(ws_size / ((size_t)NB * sizeof(int)));
    if (C > 512) C = 512;
    if (C < 1) C = 1;
    const int chunk = (N + C - 1) / C;
    const size_t lds = (size_t)NB * sizeof(int);

    // Zero the scattered region (unfilled slots must be 0; d_out is poisoned).
    hipMemsetAsync(d_out, 0, (size_t)pad_to * 3 * sizeof(float), stream);

    k_bucket_hist<<<C, 256, lds, stream>>>(coords, seps, B, hash_op, N, NB, chunk,
                                           out_bucket, chunk_hist);
    k_prefix<<<(NB + 255) / 256, 256, 0, stream>>>(chunk_hist, C, NB, out_counts);
    k_scatter<<<C, 256, lds, stream>>>(coords, out_bucket, chunk_hist, N, NB, chunk, out);
}

// Round 3
// 241.101 us; speedup vs baseline: 1.5777x; 1.5777x over previous
//
#include <hip/hip_runtime.h>
#include <stdint.h>

#define PR1 73856093u
#define PR2 19349663u
#define PR3 83492791u
#define PR4 2654435761u
#define GS  32      // chunks per scan group
#define PPT 4       // points per thread per turn-round in k_scatter

// Branch-free uniform-divisor mod: q = floor(h * (1/d)) via double (exact for
// h < 2^32), one conditional fixup.
__device__ __forceinline__ uint32_t fastmod(uint32_t h, uint32_t d, double inv) {
    uint32_t q = (uint32_t)((double)h * inv);
    int32_t r = (int32_t)(h - q * d);
    if (r >= (int32_t)d) r -= d;
    if (r < 0) r += d;
    return (uint32_t)r;
}

// K1: bucket per point (written as float), per-chunk histogram -> chunk_hist[c][b].
__global__ void k_bucket_hist(const float* __restrict__ coords,
                              const int* __restrict__ seps, int B,
                              const int* __restrict__ hash_op_p,
                              int N, int NB, int chunk, double invNB,
                              float* __restrict__ out_bucket,
                              int* __restrict__ chunk_hist) {
    extern __shared__ int hist[];          // NB ints
    __shared__ int s_seps[128];
    const int tid = threadIdx.x;
    for (int i = tid; i < NB; i += blockDim.x) hist[i] = 0;
    const int Bc = B < 128 ? B : 128;
    if (tid < Bc) s_seps[tid] = seps[tid];
    __syncthreads();

    const uint32_t hop = (uint32_t)hash_op_p[0];
    const int start = blockIdx.x * chunk;
    const int end   = min(start + chunk, N);
    for (int i = start + tid; i < end; i += blockDim.x) {
        const float x = coords[3 * (size_t)i + 0];
        const float y = coords[3 * (size_t)i + 1];
        const float z = coords[3 * (size_t)i + 2];
        const uint32_t vx = (uint32_t)(int32_t)floorf(x);
        const uint32_t vy = (uint32_t)(int32_t)floorf(y);
        const uint32_t vz = (uint32_t)(int32_t)floorf(z);
        uint32_t bid = 0;
        for (int j = 0; j < B; j++) {
            const int sj = (j < 128) ? s_seps[j] : seps[j];
            bid += (sj <= i) ? 1u : 0u;    // searchsorted 'right'
        }
        uint32_t h = vx * PR1 ^ vy * PR2 ^ vz * PR3 ^ (bid * PR4);
        h += hop;
        const uint32_t b = fastmod(h, (uint32_t)NB, invNB);
        out_bucket[i] = (float)b;
        atomicAdd(&hist[(int)b], 1);
    }
    __syncthreads();
    int* dst = chunk_hist + (size_t)blockIdx.x * NB;
    for (int i = tid; i < NB; i += blockDim.x) dst[i] = hist[i];
}

// K2a: per bucket, exclusive scan within each group of GS chunks (in place);
// group totals -> Sg[g][b]. Parallel over G x NB columns, coalesced.
__global__ void k_scan_group(int* __restrict__ ch, int* __restrict__ Sg,
                             int C, int NB) {
    const int b = blockIdx.x * blockDim.x + threadIdx.x;
    if (b >= NB) return;
    const int g  = blockIdx.y;
    const int c0 = g * GS;
    const int c1 = min(c0 + GS, C);
    int run = 0;
    for (int c = c0; c < c1; c++) {
        const size_t idx = (size_t)c * NB + b;
        const int v = ch[idx];
        ch[idx] = run;
        run += v;
    }
    Sg[(size_t)g * NB + b] = run;
}

// K2b: exclusive scan over group totals (in place); total -> counts (float).
__global__ void k_scan_tops(int* __restrict__ Sg, int G, int NB,
                            float* __restrict__ out_counts) {
    const int b = blockIdx.x * blockDim.x + threadIdx.x;
    if (b >= NB) return;
    int run = 0;
    for (int g = 0; g < G; g++) {
        const size_t idx = (size_t)g * NB + b;
        const int v = Sg[idx];
        Sg[idx] = run;
        run += v;
    }
    out_counts[b] = (float)run;
}

// Zero only the unwritten slots [min(count,512), 512) of each bucket
// (replaces a 48 MB memset with ~1 MB of writes).
__global__ void k_gaps(const float* __restrict__ counts, float* __restrict__ out) {
    const int b = blockIdx.x;
    const int cnt = (int)counts[b];
    const int c0 = cnt < 512 ? cnt : 512;
    for (int j = c0 + (int)threadIdx.x; j < 512; j += (int)blockDim.x) {
        float* p = out + ((size_t)b * 512 + j) * 3;
        p[0] = 0.f; p[1] = 0.f; p[2] = 0.f;
    }
}

// K3: stable within-bucket rank (arrival order) + scatter.
// LDS hist seeded with chunk base = in-group-exclusive + group base.
// Per round: each wave owns a contiguous 64*PPT segment; intra-wave stable
// rank via ballot match-mask; cross-wave ordering via wave turn loop.
__global__ __launch_bounds__(256, 4)
void k_scatter(const float* __restrict__ coords,
               const float* __restrict__ bucket_f,
               const int* __restrict__ ch,
               const int* __restrict__ Sg,
               int N, int NB, int chunk,
               float* __restrict__ out_sc) {
    extern __shared__ int hist[];          // NB running counters
    const int tid = threadIdx.x;
    const int c = blockIdx.x;
    const int g = c / GS;
    const int* r1 = ch + (size_t)c * NB;
    const int* r2 = Sg + (size_t)g * NB;
    for (int i = tid; i < NB; i += blockDim.x) hist[i] = r1[i] + r2[i];
    __syncthreads();

    const int start = c * chunk;
    const int end   = min(start + chunk, N);
    const int len   = end > start ? end - start : 0;
    const int per_round = (int)blockDim.x * PPT;     // 1024
    const int rounds = (len + per_round - 1) / per_round;
    const int lane = tid & 63;
    const int wv   = tid >> 6;
    const int nw   = (int)blockDim.x >> 6;
    const unsigned long long ltmask = ((unsigned long long)1 << lane) - 1;

    for (int rd = 0; rd < rounds; rd++) {
        const int wbase = start + rd * per_round + wv * (64 * PPT);
        int bs[PPT];
        float cx[PPT], cy[PPT], cz[PPT];
        unsigned long long mm[PPT];

        #pragma unroll
        for (int s = 0; s < PPT; s++) {
            const int i = wbase + s * 64 + lane;
            const bool v = (i < end);
            bs[s] = v ? (int)bucket_f[i] : -1;
            cx[s] = v ? coords[3 * (size_t)i + 0] : 0.f;
            cy[s] = v ? coords[3 * (size_t)i + 1] : 0.f;
            cz[s] = v ? coords[3 * (size_t)i + 2] : 0.f;
        }

        // Match masks: mm[s] = mask of lanes (this wave, sub-batch s) with the
        // same bucket as this lane. Column j = ballot(b == b_j) is uniform
        // (in SGPRs); lane j captures it via select.
        #pragma unroll
        for (int s = 0; s < PPT; s++) {
            const int b = bs[s];
            unsigned long long m = 0;
            #pragma unroll
            for (int j = 0; j < 64; j++) {
                const int bj = __builtin_amdgcn_readlane(b, j);
                const unsigned long long col = __ballot(b == bj);
                m = (lane == j) ? col : m;
            }
            mm[s] = m;
        }

        // Wave turn loop: arrival order = wave 0..nw-1, sub-batch 0..PPT-1.
        int basev[PPT];
        for (int w = 0; w < nw; w++) {
            if (wv == w) {
                #pragma unroll
                for (int s = 0; s < PPT; s++) {
                    const int leader = (int)__builtin_ctzll(mm[s]);
                    const int cnt    = (int)__builtin_popcountll(mm[s]);
                    int old = 0;
                    if (bs[s] >= 0 && lane == leader)
                        old = atomicAdd(&hist[bs[s]], cnt);
                    basev[s] = __shfl(old, leader, 64);
                }
            }
            __syncthreads();
        }

        #pragma unroll
        for (int s = 0; s < PPT; s++) {
            if (bs[s] >= 0) {
                const int r = basev[s] + (int)__builtin_popcountll(mm[s] & ltmask);
                if (r < 512) {
                    float* p = out_sc + ((size_t)bs[s] * 512 + r) * 3;
                    p[0] = cx[s]; p[1] = cy[s]; p[2] = cz[s];
                }
            }
        }
    }
}

extern "C" void kernel_launch(void* const* d_in, const int* in_sizes, int n_in,
                              void* d_out, int out_size, void* d_ws, size_t ws_size,
                              hipStream_t stream) {
    const float* coords  = (const float*)d_in[0];
    const int*   seps    = (const int*)d_in[1];
    const int*   hash_op = (const int*)d_in[2];

    const int N = in_sizes[0] / 3;
    const int B = in_sizes[1];
    const int pad_to = ((N + 511) / 512) * 512;
    const int NB = pad_to / 512;

    float* out        = (float*)d_out;
    float* out_counts = out + (size_t)pad_to * 3;
    float* out_bucket = out_counts + NB;

    const size_t rowbytes = (size_t)NB * sizeof(int);
    const long rows = (long)(ws_size / rowbytes);
    int C = 1024;
    while (C > 1 && (long)(C + (C + GS - 1) / GS) > rows) C--;
    if (C < 1) C = 1;
    const int G = (C + GS - 1) / GS;
    const int chunk = (N + C - 1) / C;
    int* chunk_hist = (int*)d_ws;
    int* Sg = chunk_hist + (size_t)C * NB;
    const size_t lds = rowbytes;
    const double invNB = 1.0 / (double)NB;

    k_bucket_hist<<<C, 256, lds, stream>>>(coords, seps, B, hash_op, N, NB, chunk,
                                           invNB, out_bucket, chunk_hist);
    dim3 g2a((NB + 255) / 256, G);
    k_scan_group<<<g2a, 256, 0, stream>>>(chunk_hist, Sg, C, NB);
    k_scan_tops<<<(NB + 255) / 256, 256, 0, stream>>>(Sg, G, NB, out_counts);
    k_gaps<<<NB, 64, 0, stream>>>(out_counts, out);
    k_scatter<<<C, 256, lds, stream>>>(coords, out_bucket, chunk_hist, Sg,
                                       N, NB, chunk, out);
}